// Round 2
// baseline (140.290 us; speedup 1.0000x reference)
//
#include <hip/hip_runtime.h>
#include <math.h>

// PCEN: M[t] = (1-s)*M[t-1] + s*x[t], M[0]=x[0]
//       out = (x * (M+eps)^(-alpha) + delta)^r - delta^r,  r=0.5
//
// float4 over the feature axis (80 = 20 float4) -> 16B/lane/step in flight.
// Chunked EMA over time with halo-approximated init state:
//   a=0.975, a^256 ~ 1.5e-3 -> output error ~2e-3 vs 9.56e-2 threshold.
// Chunks with t0 <= W compute exactly from t=0.

#define B_    64
#define T_    8192
#define F4_   20            // 80 f32 = 20 float4
#define NSEQ4 (B_ * F4_)    // 1280 float4-lanes per chunk
#define L_    128           // chunk length
#define C_    (T_ / L_)     // 64 chunks
#define W_    256           // halo window

__device__ __forceinline__ float pcen1(float xv, float m) {
    float g = exp2f(-0.98f * log2f(m + 1e-6f));   // (m+eps)^(-alpha)
    return sqrtf(fmaf(xv, g, 2.0f)) - 1.4142135623730951f;
}

__device__ __forceinline__ float4 pcen4(float4 xv, float4 m) {
    float4 o;
    o.x = pcen1(xv.x, m.x);
    o.y = pcen1(xv.y, m.y);
    o.z = pcen1(xv.z, m.z);
    o.w = pcen1(xv.w, m.w);
    return o;
}

__device__ __forceinline__ void ema4(float4& m, float4 xv) {
    const float s = 0.025f, a = 1.0f - 0.025f;
    m.x = fmaf(a, m.x, s * xv.x);
    m.y = fmaf(a, m.y, s * xv.y);
    m.z = fmaf(a, m.z, s * xv.z);
    m.w = fmaf(a, m.w, s * xv.w);
}

__global__ void __launch_bounds__(256)
pcen_kernel(const float4* __restrict__ x4, float4* __restrict__ o4) {
    const int bpc   = NSEQ4 / 256;             // 5 blocks per chunk
    const int chunk = blockIdx.x / bpc;        // block-uniform
    const int r     = (blockIdx.x % bpc) * 256 + threadIdx.x;
    const int b     = r / F4_;
    const int f4    = r - b * F4_;

    const size_t base = (size_t)b * (T_ * F4_) + f4;
    const float4* xp = x4 + base;              // (b, t, f4) at xp[t*F4_]
    float4*       op = o4 + base;

    const int t0 = chunk * L_;

    float4 m;
    int th;                                    // first halo timestep
    if (t0 <= W_) {                            // exact path (chunks 0..2)
        float4 x0 = xp[0];
        m = x0;                                // M[0] = x[0]
        if (chunk == 0) op[0] = pcen4(x0, m);
        th = 1;
    } else {                                   // approx: zero-init halo
        m = make_float4(0.f, 0.f, 0.f, 0.f);
        th = t0 - W_;
    }

    // halo: advance EMA over [th, t0)
    const float4* xi = xp + (size_t)th * F4_;
    const int nh = t0 - th;                    // -1 for chunk 0 -> no iters
    #pragma unroll 8
    for (int i = 0; i < nh; ++i) {
        ema4(m, *xi);
        xi += F4_;
    }

    // main: produce [tm, t0+L)
    const int tm = (chunk == 0) ? 1 : t0;
    const int n  = t0 + L_ - tm;               // 127 or 128
    xi = xp + (size_t)tm * F4_;
    float4* oi = op + (size_t)tm * F4_;
    #pragma unroll 8
    for (int i = 0; i < n; ++i) {
        float4 xv = *xi;
        ema4(m, xv);
        *oi = pcen4(xv, m);
        xi += F4_;
        oi += F4_;
    }
}

extern "C" void kernel_launch(void* const* d_in, const int* in_sizes, int n_in,
                              void* d_out, int out_size, void* d_ws, size_t ws_size,
                              hipStream_t stream) {
    const float4* x4 = (const float4*)d_in[0];
    float4*       o4 = (float4*)d_out;

    const int blocks = C_ * (NSEQ4 / 256);     // 64 * 5 = 320
    pcen_kernel<<<dim3(blocks), dim3(256), 0, stream>>>(x4, o4);
}

// Round 3
// 117.844 us; speedup vs baseline: 1.1905x; 1.1905x over previous
//
#include <hip/hip_runtime.h>
#include <math.h>

// PCEN, exact 3-kernel chunked scan:
//   K1: per-(seq4,chunk) local EMA partial sums   (L=32, C=256 -> 5120 waves)
//   K2: per-seq4 serial combine over 256 chunks, store exact chunk-start states
//   K3: per-(seq4,chunk) exact EMA + pcen map, write out
//
// M[t] = a*M[t-1] + s*x[t], M[0]=x[0];  a=0.975, a^32 = 0.44478249
// out  = sqrt(x*(M+eps)^-0.98 + 2) - sqrt(2)

#define B_    64
#define T_    8192
#define F4_   20              // 80 f32 = 20 float4
#define NSEQ4 (B_ * F4_)      // 1280 float4 sequences
#define L_    32              // chunk length
#define C_    (T_ / L_)       // 256 chunks
#define BPC_  (NSEQ4 / 256)   // 5 blocks per chunk
#define AL_   0.44478249f     // 0.975^32

__device__ __forceinline__ float pcen1(float xv, float m) {
    float g = exp2f(-0.98f * log2f(m + 1e-6f));   // (m+eps)^(-alpha)
    return sqrtf(fmaf(xv, g, 2.0f)) - 1.4142135623730951f;
}

__device__ __forceinline__ float4 pcen4(float4 xv, float4 m) {
    float4 o;
    o.x = pcen1(xv.x, m.x);
    o.y = pcen1(xv.y, m.y);
    o.z = pcen1(xv.z, m.z);
    o.w = pcen1(xv.w, m.w);
    return o;
}

__device__ __forceinline__ void ema4(float4& m, float4 xv) {
    const float s = 0.025f, a = 1.0f - 0.025f;
    m.x = fmaf(a, m.x, s * xv.x);
    m.y = fmaf(a, m.y, s * xv.y);
    m.z = fmaf(a, m.z, s * xv.z);
    m.w = fmaf(a, m.w, s * xv.w);
}

// ---- K1: local zero-init EMA over each chunk -> ws[c][r] ----
__global__ void __launch_bounds__(256)
k1_localsum(const float4* __restrict__ x4, float4* __restrict__ ws4) {
    const int chunk = blockIdx.x / BPC_;                  // block-uniform
    const int r     = (blockIdx.x % BPC_) * 256 + threadIdx.x;
    const int b     = r / F4_;
    const int f4    = r - b * F4_;

    const float4* xi = x4 + (size_t)b * (T_ * F4_) + (size_t)(chunk * L_) * F4_ + f4;

    float4 m;
    int j0;
    if (chunk == 0) {           // exact: M[0] = x[0]
        m = xi[0];
        xi += F4_;
        j0 = 1;
    } else {                    // zero-init partial
        m = make_float4(0.f, 0.f, 0.f, 0.f);
        j0 = 0;
    }

    #pragma unroll 8
    for (int j = j0; j < L_; ++j) {
        ema4(m, *xi);
        xi += F4_;
    }
    ws4[(size_t)chunk * NSEQ4 + r] = m;
}

// ---- K2: serial combine across chunks; ws[c][r] <- exact M[c*L - 1] ----
__global__ void __launch_bounds__(256)
k2_scan(float4* __restrict__ ws4) {
    const int r = blockIdx.x * 256 + threadIdx.x;
    if (r >= NSEQ4) return;

    float4 e = ws4[r];                         // exact M[L-1] (chunk 0 end)
    for (int c = 1; c < C_; ++c) {
        float4* p = ws4 + (size_t)c * NSEQ4 + r;
        float4 ls = *p;                        // local partial of chunk c
        *p = e;                                // exact start state for chunk c
        e.x = fmaf(AL_, e.x, ls.x);            // E[c] = a^L * E[c-1] + ls
        e.y = fmaf(AL_, e.y, ls.y);
        e.z = fmaf(AL_, e.z, ls.z);
        e.w = fmaf(AL_, e.w, ls.w);
    }
}

// ---- K3: exact EMA from carry + pcen map ----
__global__ void __launch_bounds__(256)
k3_apply(const float4* __restrict__ x4, const float4* __restrict__ ws4,
         float4* __restrict__ o4) {
    const int chunk = blockIdx.x / BPC_;
    const int r     = (blockIdx.x % BPC_) * 256 + threadIdx.x;
    const int b     = r / F4_;
    const int f4    = r - b * F4_;

    const size_t off = (size_t)b * (T_ * F4_) + (size_t)(chunk * L_) * F4_ + f4;
    const float4* xi = x4 + off;
    float4*       oi = o4 + off;

    float4 m;
    int j0;
    if (chunk == 0) {
        float4 x0 = xi[0];
        m = x0;                                // M[0] = x[0]
        oi[0] = pcen4(x0, m);
        xi += F4_; oi += F4_;
        j0 = 1;
    } else {
        m = ws4[(size_t)chunk * NSEQ4 + r];    // exact M[chunk*L - 1]
        j0 = 0;
    }

    #pragma unroll 8
    for (int j = j0; j < L_; ++j) {
        float4 xv = *xi;
        ema4(m, xv);
        *oi = pcen4(xv, m);
        xi += F4_; oi += F4_;
    }
}

extern "C" void kernel_launch(void* const* d_in, const int* in_sizes, int n_in,
                              void* d_out, int out_size, void* d_ws, size_t ws_size,
                              hipStream_t stream) {
    const float4* x4  = (const float4*)d_in[0];
    float4*       o4  = (float4*)d_out;
    float4*       ws4 = (float4*)d_ws;         // C_*NSEQ4*16B = 5.24 MB

    const int blocks = C_ * BPC_;               // 256*5 = 1280
    k1_localsum<<<dim3(blocks), dim3(256), 0, stream>>>(x4, ws4);
    k2_scan    <<<dim3(BPC_),   dim3(256), 0, stream>>>(ws4);
    k3_apply   <<<dim3(blocks), dim3(256), 0, stream>>>(x4, ws4, o4);
}

// Round 4
// 105.836 us; speedup vs baseline: 1.3255x; 1.1135x over previous
//
#include <hip/hip_runtime.h>
#include <math.h>

// PCEN, exact-to-1e-6 2-phase chunked scan (serial combine eliminated):
//   zfill: zero 15 pad slots at the front of ws
//   K1: per-(seq4,chunk) zero-init local EMA partial sum ls(c) -> ws[c+15]
//   K3: per-(seq4,chunk) carry = 16-term Horner over ws slots (a^(16L)~2e-6
//       truncation; exact for chunk<16 via zero pad), then EMA+pcen, write out.
//
// M[t] = a*M[t-1] + s*x[t], M[0]=x[0];  a=0.975, a^32 = 0.44478247
// out  = sqrt(x*(M+eps)^-0.98 + 2) - sqrt(2)

#define B_    64
#define T_    8192
#define F4_   20              // 80 f32 = 20 float4
#define NSEQ4 (B_ * F4_)      // 1280 float4 sequences
#define L_    32              // chunk length
#define C_    (T_ / L_)       // 256 chunks
#define BPC_  (NSEQ4 / 256)   // 5 blocks per chunk
#define H_    16              // carry horizon in chunks: (a^L)^16 ~ 2.3e-6
#define PAD_  (H_ - 1)        // 15 zero slots in front of ws
#define AL_   0.44478247f     // 0.975^32

__device__ __forceinline__ float pcen1(float xv, float m) {
    float g = exp2f(-0.98f * log2f(m + 1e-6f));   // (m+eps)^(-alpha)
    return sqrtf(fmaf(xv, g, 2.0f)) - 1.4142135623730951f;
}

__device__ __forceinline__ float4 pcen4(float4 xv, float4 m) {
    float4 o;
    o.x = pcen1(xv.x, m.x);
    o.y = pcen1(xv.y, m.y);
    o.z = pcen1(xv.z, m.z);
    o.w = pcen1(xv.w, m.w);
    return o;
}

__device__ __forceinline__ void ema4(float4& m, float4 xv) {
    const float s = 0.025f, a = 1.0f - 0.025f;
    m.x = fmaf(a, m.x, s * xv.x);
    m.y = fmaf(a, m.y, s * xv.y);
    m.z = fmaf(a, m.z, s * xv.z);
    m.w = fmaf(a, m.w, s * xv.w);
}

// ---- zero the PAD_ front slots of ws ----
__global__ void __launch_bounds__(256)
zfill(float4* __restrict__ ws4) {
    int i = blockIdx.x * 256 + threadIdx.x;
    if (i < PAD_ * NSEQ4) ws4[i] = make_float4(0.f, 0.f, 0.f, 0.f);
}

// ---- K1: local zero-init EMA over each chunk -> ws slot (chunk+PAD_) ----
__global__ void __launch_bounds__(256)
k1_localsum(const float4* __restrict__ x4, float4* __restrict__ ws4) {
    const int chunk = blockIdx.x / BPC_;                  // block-uniform
    const int r     = (blockIdx.x % BPC_) * 256 + threadIdx.x;
    const int b     = r / F4_;
    const int f4    = r - b * F4_;

    const float4* xi = x4 + (size_t)b * (T_ * F4_) + (size_t)(chunk * L_) * F4_ + f4;

    float4 m;
    int j0;
    if (chunk == 0) {           // exact: M[0] = x[0]
        m = xi[0];
        xi += F4_;
        j0 = 1;
    } else {                    // zero-init partial
        m = make_float4(0.f, 0.f, 0.f, 0.f);
        j0 = 0;
    }

    #pragma unroll 8
    for (int j = j0; j < L_; ++j) {
        ema4(m, *xi);
        xi += F4_;
    }
    ws4[(size_t)(chunk + PAD_) * NSEQ4 + r] = m;
}

// ---- K3: carry via 16-term Horner over ws, then exact EMA + pcen ----
__global__ void __launch_bounds__(256)
k3_apply(const float4* __restrict__ x4, const float4* __restrict__ ws4,
         float4* __restrict__ o4) {
    const int chunk = blockIdx.x / BPC_;
    const int r     = (blockIdx.x % BPC_) * 256 + threadIdx.x;
    const int b     = r / F4_;
    const int f4    = r - b * F4_;

    const size_t off = (size_t)b * (T_ * F4_) + (size_t)(chunk * L_) * F4_ + f4;
    const float4* xi = x4 + off;
    float4*       oi = o4 + off;

    float4 m;
    int j0;
    if (chunk == 0) {
        float4 x0 = xi[0];
        m = x0;                                // M[0] = x[0]
        oi[0] = pcen4(x0, m);
        xi += F4_; oi += F4_;
        j0 = 1;
    } else {
        // padded slots [chunk-1 .. chunk+14] = real chunks [chunk-16 .. chunk-1]
        // Horner oldest->newest: m = sum_k AL^k * ls(chunk-1-k), k=0..15
        const float4* wp = ws4 + (size_t)(chunk - 1) * NSEQ4 + r;
        float4 e = wp[0];
        #pragma unroll
        for (int k = 1; k < H_; ++k) {
            float4 ls = wp[(size_t)k * NSEQ4];
            e.x = fmaf(AL_, e.x, ls.x);
            e.y = fmaf(AL_, e.y, ls.y);
            e.z = fmaf(AL_, e.z, ls.z);
            e.w = fmaf(AL_, e.w, ls.w);
        }
        m = e;
        j0 = 0;
    }

    #pragma unroll 8
    for (int j = j0; j < L_; ++j) {
        float4 xv = *xi;
        ema4(m, xv);
        *oi = pcen4(xv, m);
        xi += F4_; oi += F4_;
    }
}

extern "C" void kernel_launch(void* const* d_in, const int* in_sizes, int n_in,
                              void* d_out, int out_size, void* d_ws, size_t ws_size,
                              hipStream_t stream) {
    const float4* x4  = (const float4*)d_in[0];
    float4*       o4  = (float4*)d_out;
    float4*       ws4 = (float4*)d_ws;          // (C_+PAD_)*NSEQ4*16B = 5.55 MB

    const int zblocks = (PAD_ * NSEQ4 + 255) / 256;   // 75
    const int blocks  = C_ * BPC_;                    // 1280

    zfill      <<<dim3(zblocks), dim3(256), 0, stream>>>(ws4);
    k1_localsum<<<dim3(blocks),  dim3(256), 0, stream>>>(x4, ws4);
    k3_apply   <<<dim3(blocks),  dim3(256), 0, stream>>>(x4, ws4, o4);
}